// Round 1
// baseline (5164.248 us; speedup 1.0000x reference)
//
#include <hip/hip_runtime.h>
#include <hip/hip_bf16.h>

// BiLSTM-CRF. Sizes fixed per reference.
#define T_LEN 4096
#define E_DIM 300
#define HD 128          // per-direction hidden
#define G4 512          // 4*HD
#define KCRF 11
#define START_TAG 9
#define STOP_TAG 10

// ---------------- Kernel A0: pre-transpose Wih into K-major Bmat[320][1024] ----------------
// Bmat[k][j] = (k<300) ? Wih_{f|b}[j][k] : 0   (j<512 -> f, else b). K padded 300->320.
__global__ void prep_B(const float* __restrict__ Wih_f, const float* __restrict__ Wih_b,
                       float* __restrict__ Bmat) {
    int idx = blockIdx.x * 256 + threadIdx.x;
    if (idx >= 320 * 1024) return;
    int k = idx >> 10, j = idx & 1023;
    float v = 0.f;
    if (k < E_DIM) v = (j < 512) ? Wih_f[j * E_DIM + k] : Wih_b[(j - 512) * E_DIM + k];
    Bmat[idx] = v;
}

// ---------------- Kernel A: xw[t][j] = emb[t] . Wih_row(j) + bih+bhh ----------------
// C[4096][1024] = gather(word_embed)[4096][300] x Bmat[300][1024], tiled 128x128, BK=32.
__global__ __launch_bounds__(256)
void gemm_xw(const int* __restrict__ inputs, const float* __restrict__ word_embed,
             const float* __restrict__ Bmat,
             const float* __restrict__ bih_f, const float* __restrict__ bhh_f,
             const float* __restrict__ bih_b, const float* __restrict__ bhh_b,
             float* __restrict__ xw) {
    __shared__ float Ast[32][128];   // transposed A tile: Ast[k][m]
    __shared__ float Bst[32][128];   // Bst[k][j]
    const int tid = threadIdx.x;
    const int row0 = blockIdx.x * 128;   // t
    const int col0 = blockIdx.y * 128;   // j
    const int tx = tid & 15, ty = tid >> 4;
    float acc[8][8] = {};

    for (int kt = 0; kt < 10; ++kt) {
        // stage A (gathered embedding rows), float4 loads, transposed LDS store
        #pragma unroll
        for (int i = 0; i < 4; ++i) {
            int slot = i * 256 + tid;          // 1024 float4 slots
            int m = slot >> 3, q = slot & 7;   // q = float4 within 32-float k-chunk
            int kf4 = kt * 8 + q;              // float4 index within 300-float row (0..79)
            float4 v = make_float4(0.f, 0.f, 0.f, 0.f);
            if (kf4 < 75) {                    // 300/4 = 75 exactly, no straddle
                int widx = inputs[row0 + m];
                v = *(const float4*)(word_embed + (size_t)widx * E_DIM + kf4 * 4);
            }
            Ast[q * 4 + 0][m] = v.x; Ast[q * 4 + 1][m] = v.y;
            Ast[q * 4 + 2][m] = v.z; Ast[q * 4 + 3][m] = v.w;
        }
        // stage B (already K-major, coalesced copy)
        #pragma unroll
        for (int i = 0; i < 4; ++i) {
            int slot = i * 256 + tid;
            int kk = slot >> 5, j4 = slot & 31;
            float4 v = *(const float4*)(Bmat + (size_t)(kt * 32 + kk) * 1024 + col0 + j4 * 4);
            *(float4*)(&Bst[kk][j4 * 4]) = v;
        }
        __syncthreads();
        #pragma unroll
        for (int kk = 0; kk < 32; ++kk) {
            float4 a0 = *(const float4*)(&Ast[kk][ty * 8]);
            float4 a1 = *(const float4*)(&Ast[kk][ty * 8 + 4]);
            float4 b0 = *(const float4*)(&Bst[kk][tx * 8]);
            float4 b1 = *(const float4*)(&Bst[kk][tx * 8 + 4]);
            float av[8] = {a0.x, a0.y, a0.z, a0.w, a1.x, a1.y, a1.z, a1.w};
            float bv[8] = {b0.x, b0.y, b0.z, b0.w, b1.x, b1.y, b1.z, b1.w};
            #pragma unroll
            for (int u = 0; u < 8; ++u)
                #pragma unroll
                for (int w = 0; w < 8; ++w) acc[u][w] += av[u] * bv[w];
        }
        __syncthreads();
    }
    #pragma unroll
    for (int u = 0; u < 8; ++u) {
        int trow = row0 + ty * 8 + u;
        #pragma unroll
        for (int w = 0; w < 8; ++w) {
            int j = col0 + tx * 8 + w;
            float bias = (j < 512) ? (bih_f[j] + bhh_f[j]) : (bih_b[j - 512] + bhh_b[j - 512]);
            xw[(size_t)trow * 1024 + j] = acc[u][w] + bias;
        }
    }
}

// ---------------- Kernel B: LSTM recurrence, one block per direction ----------------
// xw layout [T][1024]: cols 0..511 forward gates, 512..1023 backward gates.
// hbuf layout [T][256]: 0..127 h_f, 128..255 h_b.
__global__ __launch_bounds__(512, 2)
void lstm_kernel(const float* __restrict__ xw, const float* __restrict__ Whh_f,
                 const float* __restrict__ Whh_b, float* __restrict__ hbuf) {
    const int dir = blockIdx.x;
    const int j = threadIdx.x;  // 0..511: owns gate pre-activation z[j]
    const float* __restrict__ Whh = dir ? Whh_b : Whh_f;

    // Whh row j -> 128 VGPRs
    float4 w[32];
    const float4* wrow = (const float4*)(Whh + (size_t)j * HD);
    #pragma unroll
    for (int q = 0; q < 32; ++q) w[q] = wrow[q];

    __shared__ float h_lds[HD];
    __shared__ float zact[G4];
    if (j < HD) h_lds[j] = 0.f;
    float c = 0.f;
    __syncthreads();

    const int dt = dir ? -1 : 1;
    int t = dir ? (T_LEN - 1) : 0;
    const float* xp = xw + (size_t)t * 1024 + dir * 512 + j;
    float xw_cur = *xp;
    const float4* __restrict__ h4p = (const float4*)h_lds;

    for (int s = 0; s < T_LEN; ++s) {
        // prefetch next step's input projection (hidden under the dot product)
        const float* xpn = xp + dt * 1024;
        float xw_nxt = (s + 1 < T_LEN) ? *xpn : 0.f;

        float a0 = 0.f, a1 = 0.f, a2 = 0.f, a3 = 0.f;
        #pragma unroll
        for (int q = 0; q < 32; ++q) {
            float4 h4 = h4p[q];     // wave-uniform address -> LDS broadcast
            a0 += h4.x * w[q].x;
            a1 += h4.y * w[q].y;
            a2 += h4.z * w[q].z;
            a3 += h4.w * w[q].w;
        }
        float z = xw_cur + ((a0 + a2) + (a1 + a3));
        // gate order: i(0..127) f(128..255) g(256..383) o(384..511)
        float a;
        if (j >= 2 * HD && j < 3 * HD) a = tanhf(z);
        else                           a = 1.f / (1.f + __expf(-z));
        zact[j] = a;
        __syncthreads();
        if (j < HD) {
            float ig = zact[j], fg = zact[HD + j], gg = zact[2 * HD + j], og = zact[3 * HD + j];
            c = fg * c + ig * gg;
            float h = og * tanhf(c);
            h_lds[j] = h;
            hbuf[(size_t)t * 256 + (dir << 7) + j] = h;
        }
        __syncthreads();
        xw_cur = xw_nxt;
        xp = xpn;
        t += dt;
    }
}

// ---------------- Kernel C: feats[t][k] = hbuf[t] . fc_W[k] + fc_b[k] ----------------
__global__ __launch_bounds__(128)
void fc_kernel(const float* __restrict__ hbuf, const float* __restrict__ fc_W,
               const float* __restrict__ fc_b, float* __restrict__ feats) {
    int tid = threadIdx.x;
    if (tid >= 8 * KCRF) return;
    int tl = tid / KCRF, k = tid % KCRF;
    int t = blockIdx.x * 8 + tl;
    const float4* h4 = (const float4*)(hbuf + (size_t)t * 256);
    const float4* w4 = (const float4*)(fc_W + (size_t)k * 256);
    float a0 = 0.f, a1 = 0.f, a2 = 0.f, a3 = 0.f;
    #pragma unroll
    for (int q = 0; q < 64; ++q) {
        float4 h = h4[q], w = w4[q];
        a0 += h.x * w.x; a1 += h.y * w.y; a2 += h.z * w.z; a3 += h.w * w.w;
    }
    feats[t * KCRF + k] = ((a0 + a2) + (a1 + a3)) + fc_b[k];
}

// ---------------- Kernel D: gold score + CRF forward scan + final ----------------
__global__ __launch_bounds__(128)
void crf_kernel(const float* __restrict__ feats, const int* __restrict__ tags,
                const float* __restrict__ trans, float* __restrict__ out) {
    const int tid = threadIdx.x;
    __shared__ float red[128];
    __shared__ float fbuf[2][64 * KCRF];
    __shared__ float sgold;
    __shared__ float aout[KCRF];

    // ---- gold path score (parallel reduction) ----
    float p = 0.f;
    for (int i = tid; i < T_LEN + 1; i += 128) {
        int from = (i == 0) ? START_TAG : tags[i - 1];
        int to = (i == T_LEN) ? START_TAG : tags[i];
        p += trans[from * KCRF + to];
    }
    for (int t = tid; t < T_LEN; t += 128) p += feats[t * KCRF + tags[t]];
    red[tid] = p;
    __syncthreads();
    for (int s = 64; s > 0; s >>= 1) {
        if (tid < s) red[tid] += red[tid + s];
        __syncthreads();
    }
    if (tid == 0) sgold = red[0];

    // preload feats chunk 0 (64 rows)
    for (int i = tid; i < 64 * KCRF; i += 128) fbuf[0][i] = feats[i];
    __syncthreads();

    // ---- CRF forward scan: lane j (<11) owns alpha[j]; wave1 prefetches feats ----
    float alpha = (tid == START_TAG) ? 0.f : -1000.f;
    float tc[KCRF];
    if (tid < KCRF) {
        #pragma unroll
        for (int i = 0; i < KCRF; ++i) tc[i] = trans[i * KCRF + tid];  // column j
    }
    for (int chunk = 0; chunk < 64; ++chunk) {
        if (tid >= 64) {
            int nc = chunk + 1;
            if (nc < 64)
                for (int i = tid - 64; i < 64 * KCRF; i += 64)
                    fbuf[nc & 1][i] = feats[nc * 64 * KCRF + i];
        } else if (tid < KCRF) {
            const float* fb = fbuf[chunk & 1];
            for (int s = 0; s < 64; ++s) {
                float f = fb[s * KCRF + tid];
                float sc[KCRF];
                #pragma unroll
                for (int i = 0; i < KCRF; ++i) sc[i] = __shfl(alpha, i, 64) + tc[i];
                // max tree
                float m01 = fmaxf(sc[0], sc[1]), m23 = fmaxf(sc[2], sc[3]);
                float m45 = fmaxf(sc[4], sc[5]), m67 = fmaxf(sc[6], sc[7]);
                float m89 = fmaxf(sc[8], sc[9]);
                float ma = fmaxf(fmaxf(m01, m23), fmaxf(m45, m67));
                float m = fmaxf(fmaxf(m89, sc[10]), ma);
                float sum = 0.f;
                #pragma unroll
                for (int i = 0; i < KCRF; ++i) sum += __expf(sc[i] - m);
                alpha = f + m + __logf(sum);
            }
        }
        __syncthreads();
    }
    if (tid < KCRF) aout[tid] = alpha + trans[tid * KCRF + STOP_TAG];
    __syncthreads();
    if (tid == 0) {
        float m = aout[0];
        for (int i = 1; i < KCRF; ++i) m = fmaxf(m, aout[i]);
        float s = 0.f;
        for (int i = 0; i < KCRF; ++i) s += __expf(aout[i] - m);
        out[0] = (m + __logf(s)) - sgold;
    }
}

extern "C" void kernel_launch(void* const* d_in, const int* in_sizes, int n_in,
                              void* d_out, int out_size, void* d_ws, size_t ws_size,
                              hipStream_t stream) {
    const int*   inputs     = (const int*)d_in[0];
    const int*   tags       = (const int*)d_in[1];
    const float* word_embed = (const float*)d_in[2];
    const float* Wih_f      = (const float*)d_in[3];
    const float* Whh_f      = (const float*)d_in[4];
    const float* bih_f      = (const float*)d_in[5];
    const float* bhh_f      = (const float*)d_in[6];
    const float* Wih_b      = (const float*)d_in[7];
    const float* Whh_b      = (const float*)d_in[8];
    const float* bih_b      = (const float*)d_in[9];
    const float* bhh_b      = (const float*)d_in[10];
    const float* fc_W       = (const float*)d_in[11];
    const float* fc_b       = (const float*)d_in[12];
    const float* trans      = (const float*)d_in[13];
    float* out = (float*)d_out;

    // workspace layout (floats): Bmat[320*1024] | xw[4096*1024] | hbuf[4096*256] | feats[4096*11]
    float* w = (float*)d_ws;
    float* Bmat  = w;
    float* xw    = Bmat + 320 * 1024;
    float* hbuf  = xw + (size_t)T_LEN * 1024;
    float* feats = hbuf + (size_t)T_LEN * 256;

    prep_B<<<1280, 256, 0, stream>>>(Wih_f, Wih_b, Bmat);
    gemm_xw<<<dim3(32, 8), 256, 0, stream>>>(inputs, word_embed, Bmat,
                                             bih_f, bhh_f, bih_b, bhh_b, xw);
    lstm_kernel<<<2, 512, 0, stream>>>(xw, Whh_f, Whh_b, hbuf);
    fc_kernel<<<T_LEN / 8, 128, 0, stream>>>(hbuf, fc_W, fc_b, feats);
    crf_kernel<<<1, 128, 0, stream>>>(feats, tags, trans, out);
}